// Round 7
// baseline (183.688 us; speedup 1.0000x reference)
//
#include <hip/hip_runtime.h>
#include <cmath>

#define NNODES 4096
#define FDIM 512
#define DH 64
#define CAP 128

// clang builtin vector type: __builtin_nontemporal_load rejects
// HIP_vector_type<float,4>* but accepts ext_vector_type pointers.
typedef float f32x4 __attribute__((ext_vector_type(4)));

// ---------------------------------------------------------------------------
// R14 = R13 with the nontemporal-builtin type error fixed (f32x4 alias).
// R13 intent: best-measured R8 4-kernel structure (176.3us) +
// (a) non-temporal adj/feat streams in K1, (b) 2x-unrolled weight pass in
// K2/K3 (two independent er-gathers in flight per iteration).
// Persistent-kernel / occupancy arcs closed: dispatch boundaries are the
// cheap grid barrier on MI355X; K2/K3 TLP was not the bottleneck.
// ---------------------------------------------------------------------------

// ---------------------------------------------------------------------------
// Kernel 1 (heterogeneous): blocks [0,1024) run layer-0 mm+proj; blocks
// [1024,1024+4096) build neighbor lists (one block per adjacency row).
// ---------------------------------------------------------------------------
__global__ __launch_bounds__(256) void k_mm0_build(
    const float* __restrict__ adj, int* __restrict__ nbr, int* __restrict__ deg,
    const float* __restrict__ feat, const float* __restrict__ W0,
    const float* __restrict__ al0, const float* __restrict__ ar0,
    float* __restrict__ x, float* __restrict__ el, float* __restrict__ er)
{
    __shared__ float feat_s[4][FDIM];   // 8 KB (mm role)
    __shared__ float part[4][4][DH];    // 4 KB (mm role)
    __shared__ int cnt;                 // build role
    const int lane = threadIdx.x & 63;

    if (blockIdx.x >= NNODES / 4) {
        const int row = blockIdx.x - NNODES / 4;
        if (threadIdx.x == 0) cnt = 0;
        __syncthreads();
        const f32x4* arow = reinterpret_cast<const f32x4*>(adj + (size_t)row * NNODES);
        int* nrow = nbr + (size_t)row * CAP;
        // adj is streamed exactly once -> non-temporal (don't thrash L2/IF
        // for the mm role's W0/feat and the next kernels' x/el/er).
        f32x4 v[4];
        v[0] = __builtin_nontemporal_load(&arow[threadIdx.x]);
        v[1] = __builtin_nontemporal_load(&arow[threadIdx.x + 256]);
        v[2] = __builtin_nontemporal_load(&arow[threadIdx.x + 512]);
        v[3] = __builtin_nontemporal_load(&arow[threadIdx.x + 768]);
        const unsigned long long lmask = (1ull << lane) - 1ull;
#pragma unroll
        for (int s = 0; s < 4; s++) {
            const int colbase = (threadIdx.x + s * 256) * 4;
            float vals[4] = {v[s].x, v[s].y, v[s].z, v[s].w};
#pragma unroll
            for (int e = 0; e < 4; e++) {
                bool nz = vals[e] != 0.f;
                unsigned long long m = __ballot(nz);
                if (m) {
                    int base = 0;
                    if (lane == 0) base = atomicAdd(&cnt, __popcll(m));
                    base = __shfl(base, 0, 64);
                    if (nz) {
                        int idx = base + __popcll(m & lmask);
                        if (idx < CAP) nrow[idx] = colbase + e;
                    }
                }
            }
        }
        __syncthreads();
        if (threadIdx.x == 0) deg[row] = cnt < CAP ? cnt : CAP;
        return;
    }

    // ---- mm0+proj0: 4 nodes per block, wave = K-quarter, feat from LDS
    const int kq = threadIdx.x >> 6;
    const int r0 = blockIdx.x * 4;
    {
        const f32x4* fsrc = reinterpret_cast<const f32x4*>(feat + (size_t)r0 * FDIM);
        f32x4* fdst = reinterpret_cast<f32x4*>(&feat_s[0][0]);
        fdst[threadIdx.x] = __builtin_nontemporal_load(&fsrc[threadIdx.x]);
        fdst[threadIdx.x + 256] = __builtin_nontemporal_load(&fsrc[threadIdx.x + 256]);
    }
    __syncthreads();

    float acc[4] = {0.f, 0.f, 0.f, 0.f};
    const int k0 = kq * (FDIM / 4);
    for (int k = k0; k < k0 + FDIM / 4; k += 8) {
        float w[8];
#pragma unroll
        for (int u = 0; u < 8; u++) w[u] = W0[(k + u) * DH + lane];
#pragma unroll
        for (int r = 0; r < 4; r++) {
            float4 a0 = *reinterpret_cast<const float4*>(&feat_s[r][k]);
            float4 a1 = *reinterpret_cast<const float4*>(&feat_s[r][k + 4]);
            acc[r] = fmaf(a0.x, w[0], fmaf(a0.y, w[1], fmaf(a0.z, w[2], fmaf(a0.w, w[3], acc[r]))));
            acc[r] = fmaf(a1.x, w[4], fmaf(a1.y, w[5], fmaf(a1.z, w[6], fmaf(a1.w, w[7], acc[r]))));
        }
    }
    __syncthreads();
#pragma unroll
    for (int r = 0; r < 4; r++) part[kq][r][lane] = acc[r];
    __syncthreads();

    float xv = part[0][kq][lane] + part[1][kq][lane] + part[2][kq][lane] + part[3][kq][lane];
    const int node = r0 + kq;
    x[(size_t)node * DH + lane] = xv;
#pragma unroll
    for (int hh = 0; hh < 8; hh++) {
        float vl = xv * al0[lane * 8 + hh];
        float vr = xv * ar0[lane * 8 + hh];
#pragma unroll
        for (int off = 32; off >= 1; off >>= 1) {
            vl += __shfl_xor(vl, off, 64);
            vr += __shfl_xor(vr, off, 64);
        }
        if (lane == 0) {
            el[node * 8 + hh] = vl;
            er[node * 8 + hh] = vr;
        }
    }
}

// ---------------------------------------------------------------------------
// Kernel 2/3 (fused agg_L + mm_{L+1} + proj): block = 4 nodes, 256 threads.
// R8 structure (weights-first, LDS-parked, 8-deep aggregate), with the
// weight pass unrolled x2 so two er-gathers are in flight per iteration.
// ---------------------------------------------------------------------------
template <int PROJ_H>
__global__ __launch_bounds__(256) void k_agg_mm(
    const float* __restrict__ x_in, const float* __restrict__ el_in,
    const float* __restrict__ er_in, const int* __restrict__ nbr,
    const int* __restrict__ deg, const float* __restrict__ bias_agg,
    const float* __restrict__ W, const float* __restrict__ al,
    const float* __restrict__ ar, float* __restrict__ x_out,
    float* __restrict__ el_out, float* __restrict__ er_out)
{
    __shared__ float h_s[4][FDIM];     // 8 KB
    __shared__ float part[4][4][DH];   // 4 KB
    __shared__ float w_s[4][CAP][8];   // 16 KB
    __shared__ int   js_s[4][CAP];     // 2 KB
    const int lane = threadIdx.x & 63;
    const int wv = threadIdx.x >> 6;   // 0..3 = node within block
    const int node = blockIdx.x * 4 + wv;
    const float bv = bias_agg[lane];

    // ---- Phase A: all 8 heads of one node per wave
    {
        const int nl = lane >> 3;      // neighbor slot 0..7
        const int hh = lane & 7;       // head 0..7
        const float eli = el_in[node * 8 + hh];
        const int dg = deg[node];
        const int* nb = nbr + (size_t)node * CAP;
        const int nr = (dg + 7) >> 3;

        const int nbr0 = nb[lane];
        const int nbr1 = nb[64 + lane];

        // weight pass, unrolled x2: two independent er-gathers in flight
        float denp = 0.f;
        int r = 0;
        for (; r + 2 <= nr; r += 2) {
            const int jj0 = r * 8 + nl;
            const int jj1 = jj0 + 8;
            const int jraw0 = __shfl((jj0 & 64) ? nbr1 : nbr0, jj0 & 63, 64);
            const int jraw1 = __shfl((jj1 & 64) ? nbr1 : nbr0, jj1 & 63, 64);
            const bool v0 = jj0 < dg, v1 = jj1 < dg;
            const int j0 = v0 ? jraw0 : 0;
            const int j1 = v1 ? jraw1 : 0;
            const float e0 = er_in[j0 * 8 + hh];
            const float e1 = er_in[j1 * 8 + hh];
            float s0 = eli + e0; s0 = s0 > 0.f ? s0 : 0.2f * s0;
            float s1 = eli + e1; s1 = s1 > 0.f ? s1 : 0.2f * s1;
            const float w0 = v0 ? __expf(s0) : 0.f;
            const float w1 = v1 ? __expf(s1) : 0.f;
            w_s[wv][jj0][hh] = w0;
            w_s[wv][jj1][hh] = w1;
            if (hh == 0) { js_s[wv][jj0] = j0; js_s[wv][jj1] = j1; }
            denp += w0 + w1;
        }
        if (r < nr) {
            const int jj = r * 8 + nl;
            const int jraw = __shfl((jj & 64) ? nbr1 : nbr0, jj & 63, 64);
            const bool val = jj < dg;
            const int j = val ? jraw : 0;
            const float e = er_in[j * 8 + hh];
            float s = eli + e;
            s = s > 0.f ? s : 0.2f * s;
            const float w = val ? __expf(s) : 0.f;
            w_s[wv][jj][hh] = w;
            if (hh == 0) js_s[wv][jj] = j;
            denp += w;
        }
        denp += __shfl_xor(denp, 8, 64);
        denp += __shfl_xor(denp, 16, 64);
        denp += __shfl_xor(denp, 32, 64);

        // aggregate pass: pure pipelined gather+fma (padded w=0 slots inert)
        float acc[8] = {0.f, 0.f, 0.f, 0.f, 0.f, 0.f, 0.f, 0.f};
        const int cmax = nr * 8;
        for (int c = 0; c < cmax; c += 8) {
#pragma unroll
            for (int u = 0; u < 8; u++) {
                const int j = js_s[wv][c + u];
                float4 wa = *reinterpret_cast<const float4*>(&w_s[wv][c + u][0]);
                float4 wb = *reinterpret_cast<const float4*>(&w_s[wv][c + u][4]);
                float xv = x_in[(size_t)j * DH + lane];
                acc[0] = fmaf(wa.x, xv, acc[0]);
                acc[1] = fmaf(wa.y, xv, acc[1]);
                acc[2] = fmaf(wa.z, xv, acc[2]);
                acc[3] = fmaf(wa.w, xv, acc[3]);
                acc[4] = fmaf(wb.x, xv, acc[4]);
                acc[5] = fmaf(wb.y, xv, acc[5]);
                acc[6] = fmaf(wb.z, xv, acc[6]);
                acc[7] = fmaf(wb.w, xv, acc[7]);
            }
        }
#pragma unroll
        for (int h = 0; h < 8; h++) {
            float den = __shfl(denp, h, 64);
            float o = acc[h] / fmaxf(den, 1e-12f) + bv;
            o = o > 0.f ? o : __expf(o) - 1.f;     // elu
            h_s[wv][h * DH + lane] = o;
        }
    }
    __syncthreads();

    // ---- Phase B: mm + proj from LDS (wave = K-quarter)
    float acc[4] = {0.f, 0.f, 0.f, 0.f};
    const int k0 = wv * (FDIM / 4);
    for (int k = k0; k < k0 + FDIM / 4; k += 8) {
        float w[8];
#pragma unroll
        for (int u = 0; u < 8; u++) w[u] = W[(k + u) * DH + lane];
#pragma unroll
        for (int r = 0; r < 4; r++) {
            float4 a0 = *reinterpret_cast<const float4*>(&h_s[r][k]);
            float4 a1 = *reinterpret_cast<const float4*>(&h_s[r][k + 4]);
            acc[r] = fmaf(a0.x, w[0], fmaf(a0.y, w[1], fmaf(a0.z, w[2], fmaf(a0.w, w[3], acc[r]))));
            acc[r] = fmaf(a1.x, w[4], fmaf(a1.y, w[5], fmaf(a1.z, w[6], fmaf(a1.w, w[7], acc[r]))));
        }
    }
#pragma unroll
    for (int r = 0; r < 4; r++) part[wv][r][lane] = acc[r];
    __syncthreads();

    float xv = part[0][wv][lane] + part[1][wv][lane]
             + part[2][wv][lane] + part[3][wv][lane];
    const int onode = blockIdx.x * 4 + wv;
    x_out[(size_t)onode * DH + lane] = xv;
#pragma unroll
    for (int hh = 0; hh < PROJ_H; hh++) {
        float vl = xv * al[lane * PROJ_H + hh];
        float vr = xv * ar[lane * PROJ_H + hh];
#pragma unroll
        for (int off = 32; off >= 1; off >>= 1) {
            vl += __shfl_xor(vl, off, 64);
            vr += __shfl_xor(vr, off, 64);
        }
        if (lane == 0) {
            el_out[onode * PROJ_H + hh] = vl;
            er_out[onode * PROJ_H + hh] = vr;
        }
    }
}

// ---------------------------------------------------------------------------
// Kernel 4: final aggregate (H=1, no activation) -> d_out (R8 version).
// ---------------------------------------------------------------------------
__global__ __launch_bounds__(256) void k_agg_final(
    const float* __restrict__ x_in, const float* __restrict__ el_in,
    const float* __restrict__ er_in, const int* __restrict__ nbr,
    const int* __restrict__ deg, const float* __restrict__ bias,
    float* __restrict__ out)
{
    __shared__ float ws4[4][CAP];   // 2 KB
    __shared__ int   js4[4][CAP];   // 2 KB
    const int wv = threadIdx.x >> 6;
    const int node = blockIdx.x * 4 + wv;
    const int lane = threadIdx.x & 63;
    const float eli = el_in[node];
    const int dg = deg[node];
    const int* nb = nbr + (size_t)node * CAP;

    const int nbr0 = nb[lane];
    const int nbr1 = nb[64 + lane];
    const int nr = (dg + 63) >> 6;   // rounds of 64 (<= 2)
    float denp = 0.f;
    for (int r = 0; r < nr; r++) {
        const int jj = r * 64 + lane;
        const int jraw = r ? nbr1 : nbr0;
        const bool val = jj < dg;
        const int j = val ? jraw : 0;
        const float e = er_in[j];
        float s = eli + e;
        s = s > 0.f ? s : 0.2f * s;
        const float w = val ? __expf(s) : 0.f;
        ws4[wv][jj] = w;
        js4[wv][jj] = j;
        denp += w;
    }
#pragma unroll
    for (int off = 32; off >= 1; off >>= 1) denp += __shfl_xor(denp, off, 64);

    float acc = 0.f;
    const int cmax = (dg + 7) & ~7;  // entries [dg, cmax) were padded w=0
    for (int c = 0; c < cmax; c += 8) {
#pragma unroll
        for (int u = 0; u < 8; u++) {
            const int j = js4[wv][c + u];
            const float w = ws4[wv][c + u];
            const float xv = x_in[(size_t)j * DH + lane];
            acc = fmaf(w, xv, acc);
        }
    }
    out[(size_t)node * DH + lane] = acc / fmaxf(denp, 1e-12f) + bias[lane];
}

// ---------------------------------------------------------------------------
extern "C" void kernel_launch(void* const* d_in, const int* in_sizes, int n_in,
                              void* d_out, int out_size, void* d_ws, size_t ws_size,
                              hipStream_t stream)
{
    const float* adj  = (const float*)d_in[0];
    const float* feat = (const float*)d_in[1];
    const float* W0   = (const float*)d_in[2];
    const float* al0  = (const float*)d_in[3];
    const float* ar0  = (const float*)d_in[4];
    const float* b0   = (const float*)d_in[5];
    const float* W1   = (const float*)d_in[6];
    const float* al1  = (const float*)d_in[7];
    const float* ar1  = (const float*)d_in[8];
    const float* b1   = (const float*)d_in[9];
    const float* W2   = (const float*)d_in[10];
    const float* al2  = (const float*)d_in[11];
    const float* ar2  = (const float*)d_in[12];
    const float* b2   = (const float*)d_in[13];
    float* out = (float*)d_out;

    char* ws = (char*)d_ws;
    int*   nbr = (int*)ws;   ws += (size_t)NNODES * CAP * sizeof(int);   // 2 MB
    int*   deg = (int*)ws;   ws += (size_t)NNODES * sizeof(int);         // 16 KB
    float* x0  = (float*)ws; ws += (size_t)NNODES * DH * sizeof(float);  // 1 MB
    float* x1  = (float*)ws; ws += (size_t)NNODES * DH * sizeof(float);  // 1 MB
    float* elA = (float*)ws; ws += (size_t)NNODES * 8 * sizeof(float);   // 128 KB
    float* erA = (float*)ws; ws += (size_t)NNODES * 8 * sizeof(float);   // 128 KB
    float* elB = (float*)ws; ws += (size_t)NNODES * 8 * sizeof(float);   // 128 KB
    float* erB = (float*)ws; ws += (size_t)NNODES * 8 * sizeof(float);   // 128 KB

    // K1: layer-0 mm/proj (blocks 0..1023, first) + build (4096 blocks)
    k_mm0_build<<<NNODES / 4 + NNODES, 256, 0, stream>>>(
        adj, nbr, deg, feat, W0, al0, ar0, x0, elA, erA);

    // K2: agg0 + mm1/proj1   (x0,elA,erA -> x1,elB,erB)
    k_agg_mm<8><<<NNODES / 4, 256, 0, stream>>>(
        x0, elA, erA, nbr, deg, b0, W1, al1, ar1, x1, elB, erB);

    // K3: agg1 + mm2/proj2   (x1,elB,erB -> x0,elA,erA; PROJ_H=1)
    k_agg_mm<1><<<NNODES / 4, 256, 0, stream>>>(
        x1, elB, erB, nbr, deg, b1, W2, al2, ar2, x0, elA, erA);

    // K4: final aggregate (H=1, no act) -> out
    k_agg_final<<<NNODES / 4, 256, 0, stream>>>(x0, elA, erA, nbr, deg, b2, out);
}

// Round 8
// 179.613 us; speedup vs baseline: 1.0227x; 1.0227x over previous
//
#include <hip/hip_runtime.h>
#include <cmath>

#define NNODES 4096
#define FDIM 512
#define DH 64
#define CAP 128

// ---------------------------------------------------------------------------
// R15 = exact revert to the best-measured kernel (R1/R8 structure, 176.3us).
// Session record: heads-serial 183.4 / THIS 176.3 / 2xTLP 179.6 / +nt+ILP2
// 183.7 -> 7us spread across structurally different kernels = noise floor.
// Persistent-kernel arc: 660 -> 503us (grid-barrier cache maintenance is
// O(100us) per barrier on MI355X regardless of spelling) -> closed.
// Remaining measured time: ~100us harness poison-fills inside the timed
// region + ~13us compulsory 64MB adjacency HBM read + dispatch tails.
// ---------------------------------------------------------------------------

// ---------------------------------------------------------------------------
// Kernel 1 (heterogeneous): blocks [0,1024) run layer-0 mm+proj; blocks
// [1024,1024+4096) build neighbor lists (one block per adjacency row).
// ---------------------------------------------------------------------------
__global__ __launch_bounds__(256) void k_mm0_build(
    const float* __restrict__ adj, int* __restrict__ nbr, int* __restrict__ deg,
    const float* __restrict__ feat, const float* __restrict__ W0,
    const float* __restrict__ al0, const float* __restrict__ ar0,
    float* __restrict__ x, float* __restrict__ el, float* __restrict__ er)
{
    __shared__ float feat_s[4][FDIM];   // 8 KB (mm role)
    __shared__ float part[4][4][DH];    // 4 KB (mm role)
    __shared__ int cnt;                 // build role
    const int lane = threadIdx.x & 63;

    if (blockIdx.x >= NNODES / 4) {
        const int row = blockIdx.x - NNODES / 4;
        if (threadIdx.x == 0) cnt = 0;
        __syncthreads();
        const float4* arow = reinterpret_cast<const float4*>(adj + (size_t)row * NNODES);
        int* nrow = nbr + (size_t)row * CAP;
        float4 v[4];
        v[0] = arow[threadIdx.x];
        v[1] = arow[threadIdx.x + 256];
        v[2] = arow[threadIdx.x + 512];
        v[3] = arow[threadIdx.x + 768];
        const unsigned long long lmask = (1ull << lane) - 1ull;
#pragma unroll
        for (int s = 0; s < 4; s++) {
            const int colbase = (threadIdx.x + s * 256) * 4;
            float vals[4] = {v[s].x, v[s].y, v[s].z, v[s].w};
#pragma unroll
            for (int e = 0; e < 4; e++) {
                bool nz = vals[e] != 0.f;
                unsigned long long m = __ballot(nz);
                if (m) {
                    int base = 0;
                    if (lane == 0) base = atomicAdd(&cnt, __popcll(m));
                    base = __shfl(base, 0, 64);
                    if (nz) {
                        int idx = base + __popcll(m & lmask);
                        if (idx < CAP) nrow[idx] = colbase + e;
                    }
                }
            }
        }
        __syncthreads();
        if (threadIdx.x == 0) deg[row] = cnt < CAP ? cnt : CAP;
        return;
    }

    // ---- mm0+proj0: 4 nodes per block, wave = K-quarter, feat from LDS
    const int kq = threadIdx.x >> 6;
    const int r0 = blockIdx.x * 4;
    {
        const float4* fsrc = reinterpret_cast<const float4*>(feat + (size_t)r0 * FDIM);
        float4* fdst = reinterpret_cast<float4*>(&feat_s[0][0]);
        fdst[threadIdx.x] = fsrc[threadIdx.x];
        fdst[threadIdx.x + 256] = fsrc[threadIdx.x + 256];
    }
    __syncthreads();

    float acc[4] = {0.f, 0.f, 0.f, 0.f};
    const int k0 = kq * (FDIM / 4);
    for (int k = k0; k < k0 + FDIM / 4; k += 8) {
        float w[8];
#pragma unroll
        for (int u = 0; u < 8; u++) w[u] = W0[(k + u) * DH + lane];
#pragma unroll
        for (int r = 0; r < 4; r++) {
            float4 a0 = *reinterpret_cast<const float4*>(&feat_s[r][k]);
            float4 a1 = *reinterpret_cast<const float4*>(&feat_s[r][k + 4]);
            acc[r] = fmaf(a0.x, w[0], fmaf(a0.y, w[1], fmaf(a0.z, w[2], fmaf(a0.w, w[3], acc[r]))));
            acc[r] = fmaf(a1.x, w[4], fmaf(a1.y, w[5], fmaf(a1.z, w[6], fmaf(a1.w, w[7], acc[r]))));
        }
    }
    __syncthreads();
#pragma unroll
    for (int r = 0; r < 4; r++) part[kq][r][lane] = acc[r];
    __syncthreads();

    float xv = part[0][kq][lane] + part[1][kq][lane] + part[2][kq][lane] + part[3][kq][lane];
    const int node = r0 + kq;
    x[(size_t)node * DH + lane] = xv;
#pragma unroll
    for (int hh = 0; hh < 8; hh++) {
        float vl = xv * al0[lane * 8 + hh];
        float vr = xv * ar0[lane * 8 + hh];
#pragma unroll
        for (int off = 32; off >= 1; off >>= 1) {
            vl += __shfl_xor(vl, off, 64);
            vr += __shfl_xor(vr, off, 64);
        }
        if (lane == 0) {
            el[node * 8 + hh] = vl;
            er[node * 8 + hh] = vr;
        }
    }
}

// ---------------------------------------------------------------------------
// Kernel 2/3 (fused agg_L + mm_{L+1} + proj): block = 4 nodes, 256 threads.
// Weights-first decoupled structure (best measured).
// ---------------------------------------------------------------------------
template <int PROJ_H>
__global__ __launch_bounds__(256) void k_agg_mm(
    const float* __restrict__ x_in, const float* __restrict__ el_in,
    const float* __restrict__ er_in, const int* __restrict__ nbr,
    const int* __restrict__ deg, const float* __restrict__ bias_agg,
    const float* __restrict__ W, const float* __restrict__ al,
    const float* __restrict__ ar, float* __restrict__ x_out,
    float* __restrict__ el_out, float* __restrict__ er_out)
{
    __shared__ float h_s[4][FDIM];     // 8 KB
    __shared__ float part[4][4][DH];   // 4 KB
    __shared__ float w_s[4][CAP][8];   // 16 KB
    __shared__ int   js_s[4][CAP];     // 2 KB
    const int lane = threadIdx.x & 63;
    const int wv = threadIdx.x >> 6;   // 0..3 = node within block
    const int node = blockIdx.x * 4 + wv;
    const float bv = bias_agg[lane];

    // ---- Phase A: all 8 heads of one node per wave
    {
        const int nl = lane >> 3;      // neighbor slot 0..7
        const int hh = lane & 7;       // head 0..7
        const float eli = el_in[node * 8 + hh];
        const int dg = deg[node];
        const int* nb = nbr + (size_t)node * CAP;
        const int nr = (dg + 7) >> 3;

        // neighbor list -> registers (coalesced; garbage beyond dg unused)
        const int nbr0 = nb[lane];
        const int nbr1 = nb[64 + lane];

        // weight pass: rounds independent, er-gather is the only load
        float denp = 0.f;
        for (int r = 0; r < nr; r++) {
            const int jj = r * 8 + nl;
            const int jraw = __shfl((jj & 64) ? nbr1 : nbr0, jj & 63, 64);
            const bool val = jj < dg;
            const int j = val ? jraw : 0;
            const float e = er_in[j * 8 + hh];
            float s = eli + e;
            s = s > 0.f ? s : 0.2f * s;
            const float w = val ? __expf(s) : 0.f;
            w_s[wv][jj][hh] = w;
            if (hh == 0) js_s[wv][jj] = j;
            denp += w;
        }
        denp += __shfl_xor(denp, 8, 64);
        denp += __shfl_xor(denp, 16, 64);
        denp += __shfl_xor(denp, 32, 64);

        // aggregate pass: pure pipelined gather+fma (padded w=0 slots inert)
        float acc[8] = {0.f, 0.f, 0.f, 0.f, 0.f, 0.f, 0.f, 0.f};
        const int cmax = nr * 8;
        for (int c = 0; c < cmax; c += 8) {
#pragma unroll
            for (int u = 0; u < 8; u++) {
                const int j = js_s[wv][c + u];
                float4 wa = *reinterpret_cast<const float4*>(&w_s[wv][c + u][0]);
                float4 wb = *reinterpret_cast<const float4*>(&w_s[wv][c + u][4]);
                float xv = x_in[(size_t)j * DH + lane];
                acc[0] = fmaf(wa.x, xv, acc[0]);
                acc[1] = fmaf(wa.y, xv, acc[1]);
                acc[2] = fmaf(wa.z, xv, acc[2]);
                acc[3] = fmaf(wa.w, xv, acc[3]);
                acc[4] = fmaf(wb.x, xv, acc[4]);
                acc[5] = fmaf(wb.y, xv, acc[5]);
                acc[6] = fmaf(wb.z, xv, acc[6]);
                acc[7] = fmaf(wb.w, xv, acc[7]);
            }
        }
#pragma unroll
        for (int h = 0; h < 8; h++) {
            float den = __shfl(denp, h, 64);
            float o = acc[h] / fmaxf(den, 1e-12f) + bv;
            o = o > 0.f ? o : __expf(o) - 1.f;     // elu
            h_s[wv][h * DH + lane] = o;
        }
    }
    __syncthreads();

    // ---- Phase B: mm + proj from LDS (wave = K-quarter)
    float acc[4] = {0.f, 0.f, 0.f, 0.f};
    const int k0 = wv * (FDIM / 4);
    for (int k = k0; k < k0 + FDIM / 4; k += 8) {
        float w[8];
#pragma unroll
        for (int u = 0; u < 8; u++) w[u] = W[(k + u) * DH + lane];
#pragma unroll
        for (int r = 0; r < 4; r++) {
            float4 a0 = *reinterpret_cast<const float4*>(&h_s[r][k]);
            float4 a1 = *reinterpret_cast<const float4*>(&h_s[r][k + 4]);
            acc[r] = fmaf(a0.x, w[0], fmaf(a0.y, w[1], fmaf(a0.z, w[2], fmaf(a0.w, w[3], acc[r]))));
            acc[r] = fmaf(a1.x, w[4], fmaf(a1.y, w[5], fmaf(a1.z, w[6], fmaf(a1.w, w[7], acc[r]))));
        }
    }
#pragma unroll
    for (int r = 0; r < 4; r++) part[wv][r][lane] = acc[r];
    __syncthreads();

    float xv = part[0][wv][lane] + part[1][wv][lane]
             + part[2][wv][lane] + part[3][wv][lane];
    const int onode = blockIdx.x * 4 + wv;
    x_out[(size_t)onode * DH + lane] = xv;
#pragma unroll
    for (int hh = 0; hh < PROJ_H; hh++) {
        float vl = xv * al[lane * PROJ_H + hh];
        float vr = xv * ar[lane * PROJ_H + hh];
#pragma unroll
        for (int off = 32; off >= 1; off >>= 1) {
            vl += __shfl_xor(vl, off, 64);
            vr += __shfl_xor(vr, off, 64);
        }
        if (lane == 0) {
            el_out[onode * PROJ_H + hh] = vl;
            er_out[onode * PROJ_H + hh] = vr;
        }
    }
}

// ---------------------------------------------------------------------------
// Kernel 4: final aggregate (H=1, no activation) -> d_out.
// ---------------------------------------------------------------------------
__global__ __launch_bounds__(256) void k_agg_final(
    const float* __restrict__ x_in, const float* __restrict__ el_in,
    const float* __restrict__ er_in, const int* __restrict__ nbr,
    const int* __restrict__ deg, const float* __restrict__ bias,
    float* __restrict__ out)
{
    __shared__ float ws4[4][CAP];   // 2 KB
    __shared__ int   js4[4][CAP];   // 2 KB
    const int wv = threadIdx.x >> 6;
    const int node = blockIdx.x * 4 + wv;
    const int lane = threadIdx.x & 63;
    const float eli = el_in[node];
    const int dg = deg[node];
    const int* nb = nbr + (size_t)node * CAP;

    const int nbr0 = nb[lane];
    const int nbr1 = nb[64 + lane];
    const int nr = (dg + 63) >> 6;   // rounds of 64 (<= 2)
    float denp = 0.f;
    for (int r = 0; r < nr; r++) {
        const int jj = r * 64 + lane;
        const int jraw = r ? nbr1 : nbr0;
        const bool val = jj < dg;
        const int j = val ? jraw : 0;
        const float e = er_in[j];
        float s = eli + e;
        s = s > 0.f ? s : 0.2f * s;
        const float w = val ? __expf(s) : 0.f;
        ws4[wv][jj] = w;
        js4[wv][jj] = j;
        denp += w;
    }
#pragma unroll
    for (int off = 32; off >= 1; off >>= 1) denp += __shfl_xor(denp, off, 64);

    float acc = 0.f;
    const int cmax = (dg + 7) & ~7;  // entries [dg, cmax) were padded w=0
    for (int c = 0; c < cmax; c += 8) {
#pragma unroll
        for (int u = 0; u < 8; u++) {
            const int j = js4[wv][c + u];
            const float w = ws4[wv][c + u];
            const float xv = x_in[(size_t)j * DH + lane];
            acc = fmaf(w, xv, acc);
        }
    }
    out[(size_t)node * DH + lane] = acc / fmaxf(denp, 1e-12f) + bias[lane];
}

// ---------------------------------------------------------------------------
extern "C" void kernel_launch(void* const* d_in, const int* in_sizes, int n_in,
                              void* d_out, int out_size, void* d_ws, size_t ws_size,
                              hipStream_t stream)
{
    const float* adj  = (const float*)d_in[0];
    const float* feat = (const float*)d_in[1];
    const float* W0   = (const float*)d_in[2];
    const float* al0  = (const float*)d_in[3];
    const float* ar0  = (const float*)d_in[4];
    const float* b0   = (const float*)d_in[5];
    const float* W1   = (const float*)d_in[6];
    const float* al1  = (const float*)d_in[7];
    const float* ar1  = (const float*)d_in[8];
    const float* b1   = (const float*)d_in[9];
    const float* W2   = (const float*)d_in[10];
    const float* al2  = (const float*)d_in[11];
    const float* ar2  = (const float*)d_in[12];
    const float* b2   = (const float*)d_in[13];
    float* out = (float*)d_out;

    char* ws = (char*)d_ws;
    int*   nbr = (int*)ws;   ws += (size_t)NNODES * CAP * sizeof(int);   // 2 MB
    int*   deg = (int*)ws;   ws += (size_t)NNODES * sizeof(int);         // 16 KB
    float* x0  = (float*)ws; ws += (size_t)NNODES * DH * sizeof(float);  // 1 MB
    float* x1  = (float*)ws; ws += (size_t)NNODES * DH * sizeof(float);  // 1 MB
    float* elA = (float*)ws; ws += (size_t)NNODES * 8 * sizeof(float);   // 128 KB
    float* erA = (float*)ws; ws += (size_t)NNODES * 8 * sizeof(float);   // 128 KB
    float* elB = (float*)ws; ws += (size_t)NNODES * 8 * sizeof(float);   // 128 KB
    float* erB = (float*)ws; ws += (size_t)NNODES * 8 * sizeof(float);   // 128 KB

    // K1: layer-0 mm/proj (blocks 0..1023, first) + build (4096 blocks)
    k_mm0_build<<<NNODES / 4 + NNODES, 256, 0, stream>>>(
        adj, nbr, deg, feat, W0, al0, ar0, x0, elA, erA);

    // K2: agg0 + mm1/proj1   (x0,elA,erA -> x1,elB,erB)
    k_agg_mm<8><<<NNODES / 4, 256, 0, stream>>>(
        x0, elA, erA, nbr, deg, b0, W1, al1, ar1, x1, elB, erB);

    // K3: agg1 + mm2/proj2   (x1,elB,erB -> x0,elA,erA; PROJ_H=1)
    k_agg_mm<1><<<NNODES / 4, 256, 0, stream>>>(
        x1, elB, erB, nbr, deg, b1, W2, al2, ar2, x0, elA, erA);

    // K4: final aggregate (H=1, no act) -> out
    k_agg_final<<<NNODES / 4, 256, 0, stream>>>(x0, elA, erA, nbr, deg, b2, out);
}